// Round 5
// baseline (260.235 us; speedup 1.0000x reference)
//
#include <hip/hip_runtime.h>
#include <hip/hip_bf16.h>
#include <stdint.h>

#define BATCH 2
#define S_LEN 2048
#define EMB   1024
#define NHEAD 16
#define HDIM  64

typedef __attribute__((ext_vector_type(8)))  __bf16 bf16x8;
typedef __attribute__((ext_vector_type(4)))  __bf16 bf16x4;
typedef __attribute__((ext_vector_type(4)))  float  f32x4;
typedef __attribute__((ext_vector_type(16))) float  f32x16;

#define ZERO16 ((f32x16){0.f,0.f,0.f,0.f,0.f,0.f,0.f,0.f,0.f,0.f,0.f,0.f,0.f,0.f,0.f,0.f})
#define SM_SCALE_LOG2 0.18033688011112042f  /* 0.125 * log2(e) */

static __device__ __forceinline__ void gload_lds16(const void* g, void* l) {
    __builtin_amdgcn_global_load_lds(
        (__attribute__((address_space(1))) void*)g,
        (__attribute__((address_space(3))) void*)l,
        16, 0, 0);
}

// ---------------------------------------------------------------------------
// fp32 -> bf16 conversions
// ---------------------------------------------------------------------------
__global__ void f2b_kernel(const float* __restrict__ s, __bf16* __restrict__ d, int n4) {
    int i = blockIdx.x * blockDim.x + threadIdx.x;
    if (i >= n4) return;
    float4 v = reinterpret_cast<const float4*>(s)[i];
    bf16x4 o = { (__bf16)v.x, (__bf16)v.y, (__bf16)v.z, (__bf16)v.w };
    reinterpret_cast<bf16x4*>(d)[i] = o;
}

__global__ void f2b4_kernel(const float* __restrict__ s0, const float* __restrict__ s1,
                            const float* __restrict__ s2, const float* __restrict__ s3,
                            __bf16* __restrict__ d0, __bf16* __restrict__ d1,
                            __bf16* __restrict__ d2, __bf16* __restrict__ d3, int n4) {
    int i = blockIdx.x * blockDim.x + threadIdx.x;
    if (i >= n4) return;
    const float* s = blockIdx.y == 0 ? s0 : blockIdx.y == 1 ? s1 : blockIdx.y == 2 ? s2 : s3;
    __bf16*      d = blockIdx.y == 0 ? d0 : blockIdx.y == 1 ? d1 : blockIdx.y == 2 ? d2 : d3;
    float4 v = reinterpret_cast<const float4*>(s)[i];
    bf16x4 o = { (__bf16)v.x, (__bf16)v.y, (__bf16)v.z, (__bf16)v.w };
    reinterpret_cast<bf16x4*>(d)[i] = o;
}

// ---------------------------------------------------------------------------
// 128x64-tile NT GEMM, fp32 output (final projection). Grid (N/64, M/128).
// 4 waves; wave w owns rows w*32..w*32+31, all 64 cols. acc 2x4 of 16x16x32.
// ---------------------------------------------------------------------------
__global__ __launch_bounds__(256)
void gemm_o64(const __bf16* __restrict__ A, const __bf16* __restrict__ W,
              const float* __restrict__ bias, float* __restrict__ out,
              int M, int N, int K) {
    __shared__ __align__(16) __bf16 As[128 * 32];
    __shared__ __align__(16) __bf16 Bs[64 * 32];

    const int t    = threadIdx.x;
    const int w    = t >> 6;
    const int lane = t & 63;
    const int m0   = blockIdx.y * 128;
    const int n0   = blockIdx.x * 64;
    const int wr   = w * 32;
    const int fr   = lane & 15;
    const int kg   = (lane >> 4) * 8;

    f32x4 acc[2][4];
#pragma unroll
    for (int i = 0; i < 2; ++i)
#pragma unroll
        for (int n = 0; n < 4; ++n) acc[i][n] = (f32x4){0.f, 0.f, 0.f, 0.f};

    for (int kt = 0; kt < K; kt += 32) {
#pragma unroll
        for (int i = 0; i < 2; ++i) {
            int chunk = i * 256 + t;
            int row   = chunk >> 2;
            int col   = (chunk & 3) * 8;
            gload_lds16(A + (size_t)(m0 + row) * K + kt + col,
                        (char*)As + i * 4096 + w * 1024);
        }
        {
            int row = t >> 2;
            int col = (t & 3) * 8;
            gload_lds16(W + (size_t)(n0 + row) * K + kt + col,
                        (char*)Bs + w * 1024);
        }
        __syncthreads();

        bf16x8 af[2], bfv[4];
#pragma unroll
        for (int m = 0; m < 2; ++m)
            af[m] = *(const bf16x8*)&As[(wr + m * 16 + fr) * 32 + kg];
#pragma unroll
        for (int n = 0; n < 4; ++n)
            bfv[n] = *(const bf16x8*)&Bs[(n * 16 + fr) * 32 + kg];
#pragma unroll
        for (int m = 0; m < 2; ++m)
#pragma unroll
            for (int n = 0; n < 4; ++n)
                acc[m][n] = __builtin_amdgcn_mfma_f32_16x16x32_bf16(
                    af[m], bfv[n], acc[m][n], 0, 0, 0);
        __syncthreads();
    }

    const int rbase = (lane >> 4) * 4;
#pragma unroll
    for (int m = 0; m < 2; ++m) {
#pragma unroll
        for (int n = 0; n < 4; ++n) {
            int col  = n0 + n * 16 + fr;
            float bv = bias[col];
#pragma unroll
            for (int jj = 0; jj < 4; ++jj) {
                int row = m0 + wr + m * 16 + rbase + jj;
                out[(size_t)row * N + col] = acc[m][n][jj] + bv;
            }
        }
    }
}

// ---------------------------------------------------------------------------
// Fused QKV projection, 128x64 tiles: grid x = 48 (which*16 + nblk), y = 32.
// Output bf16 into [B,H,S,HD].
// ---------------------------------------------------------------------------
__global__ __launch_bounds__(256)
void gemm_qkv64(const __bf16* __restrict__ A,
                const __bf16* __restrict__ W0p, const __bf16* __restrict__ W1p,
                const __bf16* __restrict__ W2p,
                const float* __restrict__ b0p, const float* __restrict__ b1p,
                const float* __restrict__ b2p,
                __bf16* __restrict__ o0, __bf16* __restrict__ o1,
                __bf16* __restrict__ o2, int M, int N, int K) {
    __shared__ __align__(16) __bf16 As[128 * 32];
    __shared__ __align__(16) __bf16 Bs[64 * 32];

    const int which = blockIdx.x >> 4;
    const __bf16* W    = which == 0 ? W0p : which == 1 ? W1p : W2p;
    const float*  bias = which == 0 ? b0p : which == 1 ? b1p : b2p;
    __bf16*       out  = which == 0 ? o0  : which == 1 ? o1  : o2;

    const int t    = threadIdx.x;
    const int w    = t >> 6;
    const int lane = t & 63;
    const int m0   = blockIdx.y * 128;
    const int n0   = (blockIdx.x & 15) * 64;
    const int wr   = w * 32;
    const int fr   = lane & 15;
    const int kg   = (lane >> 4) * 8;

    f32x4 acc[2][4];
#pragma unroll
    for (int i = 0; i < 2; ++i)
#pragma unroll
        for (int n = 0; n < 4; ++n) acc[i][n] = (f32x4){0.f, 0.f, 0.f, 0.f};

    for (int kt = 0; kt < K; kt += 32) {
#pragma unroll
        for (int i = 0; i < 2; ++i) {
            int chunk = i * 256 + t;
            int row   = chunk >> 2;
            int col   = (chunk & 3) * 8;
            gload_lds16(A + (size_t)(m0 + row) * K + kt + col,
                        (char*)As + i * 4096 + w * 1024);
        }
        {
            int row = t >> 2;
            int col = (t & 3) * 8;
            gload_lds16(W + (size_t)(n0 + row) * K + kt + col,
                        (char*)Bs + w * 1024);
        }
        __syncthreads();

        bf16x8 af[2], bfv[4];
#pragma unroll
        for (int m = 0; m < 2; ++m)
            af[m] = *(const bf16x8*)&As[(wr + m * 16 + fr) * 32 + kg];
#pragma unroll
        for (int n = 0; n < 4; ++n)
            bfv[n] = *(const bf16x8*)&Bs[(n * 16 + fr) * 32 + kg];
#pragma unroll
        for (int m = 0; m < 2; ++m)
#pragma unroll
            for (int n = 0; n < 4; ++n)
                acc[m][n] = __builtin_amdgcn_mfma_f32_16x16x32_bf16(
                    af[m], bfv[n], acc[m][n], 0, 0, 0);
        __syncthreads();
    }

    const int rbase = (lane >> 4) * 4;
#pragma unroll
    for (int m = 0; m < 2; ++m) {
#pragma unroll
        for (int n = 0; n < 4; ++n) {
            int col  = n0 + n * 16 + fr;
            float bv = bias[col];
#pragma unroll
            for (int jj = 0; jj < 4; ++jj) {
                int row = m0 + wr + m * 16 + rbase + jj;
                float v = acc[m][n][jj] + bv;
                int b = row >> 11, s = row & (S_LEN - 1);
                int hh = col >> 6, d = col & (HDIM - 1);
                out[(((size_t)(b * NHEAD + hh)) * S_LEN + s) * HDIM + d] = (__bf16)v;
            }
        }
    }
}

// ---------------------------------------------------------------------------
// Block-causal flash attention, split-KV 8-wave, 3-blocks/CU structure.
// Grid (x=bh 32, y=16); qt = heavy-first remap of y. Block 512 thr = 8 waves;
// wave w: q-block 4qt+(w&3), kv-half h2=w>>2. 128 keys/chunk: K double-buffered
// via gload_lds (XOR-swizzled src); V single-buffered reg-transposed
// [d][key ^ (x(d)<<3)], x(d)=(d^(d>>3))&15 (2-way on both sides).
// Softmax per-lane exp2-FMA; cvt_pk packing; permlane32_swap exchange;
// defer-max; setprio around MFMA clusters. Pair merge (w, w+4) via LDS.
// ---------------------------------------------------------------------------
__global__ __launch_bounds__(512, 6)
void attn4_kernel(const __bf16* __restrict__ Q, const __bf16* __restrict__ Kv,
                  const __bf16* __restrict__ V, __bf16* __restrict__ out) {
    __shared__ __align__(16) __bf16 Kt[2][128 * 64];   // 32 KB
    __shared__ __align__(16) __bf16 Vt[64 * 128];      // 16 KB
    __shared__ float bc[8][32];                        // 1 KB

    const int t    = threadIdx.x;
    const int w8   = t >> 6;
    const int lane = t & 63;
    const int h    = lane >> 5;
    const int q32  = lane & 31;
    const int j    = w8 & 3;
    const int h2   = w8 >> 2;
    const int bh   = blockIdx.x;   // 0..31
    const int yy   = blockIdx.y;   // 0..15
    const int qt   = (yy < 8) ? (15 - yy) : (yy - 8);   // heavy-first dispatch
    const int qb   = 4 * qt + j;

    const __bf16* Qp = Q  + (size_t)bh * S_LEN * HDIM;
    const __bf16* Kp = Kv + (size_t)bh * S_LEN * HDIM;
    const __bf16* Vp = V  + (size_t)bh * S_LEN * HDIM;

    const int qrow = qb * 32 + q32;

    bf16x8 qreg[4];
#pragma unroll
    for (int ks = 0; ks < 4; ++ks)
        qreg[ks] = *(const bf16x8*)&Qp[(size_t)qrow * HDIM + 16 * ks + 8 * h];

    f32x16 oacc0 = ZERO16, oacc1 = ZERO16;
    float mrun = -1e30f, lrun = 0.f;

    // ---- prologue: stage chunk 0 ----
    {
#pragma unroll
        for (int i = 0; i < 2; ++i) {
            int c16 = i * 512 + t;
            int key = c16 >> 3;
            int d0  = ((c16 & 7) ^ (key & 7)) * 8;
            gload_lds16(Kp + (size_t)key * HDIM + d0, (char*)&Kt[0][0] + c16 * 16);
        }
        bf16x8 vr[2];
#pragma unroll
        for (int i = 0; i < 2; ++i)
            vr[i] = *(const bf16x8*)&Vp[(size_t)(64 * h2 + lane) * HDIM + (4 * i + j) * 8];
        const int key = 64 * h2 + lane;
#pragma unroll
        for (int i = 0; i < 2; ++i) {
            int d0 = (4 * i + j) * 8;
#pragma unroll
            for (int e = 0; e < 8; ++e) {
                int d = d0 + e;
                int x = (d ^ (d >> 3)) & 15;
                Vt[d * 128 + (key ^ (x << 3))] = vr[i][e];
            }
        }
        __syncthreads();
    }

    for (int c = 0; c <= qt; ++c) {
        const int  cur = c & 1;
        const bool pre = (c < qt);
        bf16x8 vr[2];
        if (pre) {
            const int kb = (c + 1) * 128;
#pragma unroll
            for (int i = 0; i < 2; ++i) {
                int c16 = i * 512 + t;
                int key = c16 >> 3;
                int d0  = ((c16 & 7) ^ (key & 7)) * 8;
                gload_lds16(Kp + (size_t)(kb + key) * HDIM + d0,
                            (char*)&Kt[cur ^ 1][0] + c16 * 16);
            }
#pragma unroll
            for (int i = 0; i < 2; ++i)
                vr[i] = *(const bf16x8*)&Vp[(size_t)(kb + 64 * h2 + lane) * HDIM +
                                            (4 * i + j) * 8];
        }

        // causal sub-block count for this wave in this chunk
        int ns;
        if (pre) ns = 2;
        else     ns = h2 ? (j == 3 ? 2 : (j == 2 ? 1 : 0)) : (j == 0 ? 1 : 2);

        for (int u = 0; u < ns; ++u) {
            const int klocal = 64 * h2 + 32 * u;

            // S^T = K . Q^T
            f32x16 sac = ZERO16;
            __builtin_amdgcn_s_setprio(1);
#pragma unroll
            for (int ks = 0; ks < 4; ++ks) {
                bf16x8 kf = *(const bf16x8*)&Kt[cur][(klocal + q32) * 64 +
                                ((16 * ks + 8 * h) ^ ((q32 & 7) << 3))];
                sac = __builtin_amdgcn_mfma_f32_32x32x16_bf16(kf, qreg[ks], sac, 0, 0, 0);
            }
            __builtin_amdgcn_s_setprio(0);

            // softmax: max tree on raw scores, scale folded into FMA
            float rmax = sac[0];
#pragma unroll
            for (int r = 1; r < 16; ++r) rmax = fmaxf(rmax, sac[r]);
            float pmax = rmax * SM_SCALE_LOG2;
            pmax = fmaxf(pmax, __shfl_xor(pmax, 32));

            if (__any(pmax > mrun + 8.f)) {
                float mnew = fmaxf(mrun, pmax);
                float fac  = exp2f(mrun - mnew);
                mrun = mnew;
                lrun *= fac;
                bc[w8][q32] = fac;
                asm volatile("s_waitcnt lgkmcnt(0)" ::: "memory");
                __builtin_amdgcn_sched_barrier(0);
#pragma unroll
                for (int q2 = 0; q2 < 4; ++q2) {
                    f32x4 fv = *(const f32x4*)&bc[w8][8 * q2 + 4 * h];
#pragma unroll
                    for (int jj = 0; jj < 4; ++jj) {
                        oacc0[4 * q2 + jj] *= fv[jj];
                        oacc1[4 * q2 + jj] *= fv[jj];
                    }
                }
            }

            float ps = 0.f;
#pragma unroll
            for (int r = 0; r < 16; ++r) {
                float pv = exp2f(__builtin_fmaf(sac[r], SM_SCALE_LOG2, -mrun));
                ps += pv;
                sac[r] = pv;
            }
            ps += __shfl_xor(ps, 32);
            lrun += ps;

            // pack P rows pairwise to bf16 (hardware cvt_pk)
            unsigned L[4], H[4];
#pragma unroll
            for (int g = 0; g < 4; ++g) {
                asm("v_cvt_pk_bf16_f32 %0, %1, %2"
                    : "=v"(L[g]) : "v"(sac[4 * g]), "v"(sac[4 * g + 1]));
                asm("v_cvt_pk_bf16_f32 %0, %1, %2"
                    : "=v"(H[g]) : "v"(sac[4 * g + 2]), "v"(sac[4 * g + 3]));
            }

            __builtin_amdgcn_s_setprio(1);
#pragma unroll
            for (int s2 = 0; s2 < 2; ++s2) {
                unsigned a0 = L[2 * s2], b0 = L[2 * s2 + 1];
                unsigned a1 = H[2 * s2], b1 = H[2 * s2 + 1];
                asm("v_permlane32_swap_b32 %0, %1" : "+v"(a0), "+v"(b0));
                asm("v_permlane32_swap_b32 %0, %1" : "+v"(a1), "+v"(b1));
                unsigned wvw[4] = { a0, a1, b0, b1 };
                bf16x8 pa = *(bf16x8*)wvw;

                const int klb = klocal + 16 * s2;
#pragma unroll
                for (int n = 0; n < 2; ++n) {
                    int d = 32 * n + q32;
                    int x = (d ^ (d >> 3)) & 15;
                    bf16x8 vf = *(const bf16x8*)&Vt[d * 128 +
                                    ((klb + 8 * h) ^ (x << 3))];
                    if (n == 0)
                        oacc0 = __builtin_amdgcn_mfma_f32_32x32x16_bf16(pa, vf, oacc0, 0, 0, 0);
                    else
                        oacc1 = __builtin_amdgcn_mfma_f32_32x32x16_bf16(pa, vf, oacc1, 0, 0, 0);
                }
            }
            __builtin_amdgcn_s_setprio(0);
        }

        __syncthreads();                 // all reads of Vt & Kt[cur] done
        if (pre) {
            const int key = 64 * h2 + lane;
#pragma unroll
            for (int i = 0; i < 2; ++i) {
                int d0 = (4 * i + j) * 8;
#pragma unroll
                for (int e = 0; e < 8; ++e) {
                    int d = d0 + e;
                    int x = (d ^ (d >> 3)) & 15;
                    Vt[d * 128 + (key ^ (x << 3))] = vr[i][e];
                }
            }
            __syncthreads();             // Vt for chunk c+1 visible
        }
    }

    // ---- pair merge: waves (j, h2=0) <- (j, h2=1) ----
    float* MLm = (float*)&Vt[0];         // [8][32]
    float* MLl = MLm + 256;              // [8][32]
    float* Oex = (float*)&Kt[0][0];      // [4][32][64] f32 = 32 KB

    if (h == 0) { MLm[w8 * 32 + q32] = mrun; MLl[w8 * 32 + q32] = lrun; }
    if (h2 == 1) {
        float* ob = Oex + j * 2048;
#pragma unroll
        for (int q2 = 0; q2 < 4; ++q2)
#pragma unroll
            for (int jj = 0; jj < 4; ++jj) {
                int r  = 4 * q2 + jj;
                int rl = 8 * q2 + 4 * h + jj;
                ob[rl * 64 + q32]      = oacc0[r];
                ob[rl * 64 + 32 + q32] = oacc1[r];
            }
    }
    __syncthreads();

    if (h2 == 0) {
        const int b = bh >> 4, hh = bh & (NHEAD - 1);
        __bf16* op = out + (size_t)b * S_LEN * EMB + hh * HDIM;
        const float* ob = Oex + j * 2048;
#pragma unroll
        for (int q2 = 0; q2 < 4; ++q2) {
            f32x4 ma4 = *(const f32x4*)&MLm[j * 32 + 8 * q2 + 4 * h];
            f32x4 mb4 = *(const f32x4*)&MLm[(j + 4) * 32 + 8 * q2 + 4 * h];
            f32x4 la4 = *(const f32x4*)&MLl[j * 32 + 8 * q2 + 4 * h];
            f32x4 lb4 = *(const f32x4*)&MLl[(j + 4) * 32 + 8 * q2 + 4 * h];
#pragma unroll
            for (int jj = 0; jj < 4; ++jj) {
                float ma = ma4[jj], mb = mb4[jj];
                float mst = fmaxf(ma, mb);
                float sa  = exp2f(ma - mst), sb = exp2f(mb - mst);
                float inv = 1.f / (la4[jj] * sa + lb4[jj] * sb);
                int r  = 4 * q2 + jj;
                int rl = 8 * q2 + 4 * h + jj;
                int row = qb * 32 + rl;
                float v0 = (oacc0[r] * sa + ob[rl * 64 + q32] * sb) * inv;
                float v1 = (oacc1[r] * sa + ob[rl * 64 + 32 + q32] * sb) * inv;
                op[(size_t)row * EMB + q32]      = (__bf16)v0;
                op[(size_t)row * EMB + 32 + q32] = (__bf16)v1;
            }
        }
    }
}

// ---------------------------------------------------------------------------
extern "C" void kernel_launch(void* const* d_in, const int* in_sizes, int n_in,
                              void* d_out, int out_size, void* d_ws, size_t ws_size,
                              hipStream_t stream) {
    const float* x  = (const float*)d_in[0];
    const float* Wq = (const float*)d_in[1];
    const float* bq = (const float*)d_in[2];
    const float* Wk = (const float*)d_in[3];
    const float* bk = (const float*)d_in[4];
    const float* Wv = (const float*)d_in[5];
    const float* bv = (const float*)d_in[6];
    const float* Wo = (const float*)d_in[7];
    const float* bo = (const float*)d_in[8];
    float* out = (float*)d_out;

    char* ws = (char*)d_ws;
    __bf16* xb  = (__bf16*)(ws + 0);
    __bf16* wqb = (__bf16*)(ws + 8388608);
    __bf16* wkb = (__bf16*)(ws + 10485760);
    __bf16* wvb = (__bf16*)(ws + 12582912);
    __bf16* wob = (__bf16*)(ws + 14680064);
    __bf16* Qb  = (__bf16*)(ws + 16777216);
    __bf16* Kb  = (__bf16*)(ws + 25165824);
    __bf16* Vb  = (__bf16*)(ws + 33554432);
    __bf16* Ab  = (__bf16*)(ws + 41943040);

    const int M = BATCH * S_LEN;  // 4096
    const int N = EMB;            // 1024
    const int K = EMB;            // 1024

    f2b_kernel<<<(M * K / 4 + 255) / 256, 256, 0, stream>>>(x, xb, M * K / 4);
    f2b4_kernel<<<dim3(N * K / 4 / 256, 4), 256, 0, stream>>>(
        Wq, Wk, Wv, Wo, wqb, wkb, wvb, wob, N * K / 4);

    gemm_qkv64<<<dim3(48, M / 128), 256, 0, stream>>>(
        xb, wqb, wkb, wvb, bq, bk, bv, Qb, Kb, Vb, M, N, K);

    attn4_kernel<<<dim3(BATCH * NHEAD, S_LEN / 128), 512, 0, stream>>>(Qb, Kb, Vb, Ab);

    gemm_o64<<<dim3(16, M / 128), 256, 0, stream>>>(Ab, wob, bo, out, M, N, K);
}

// Round 6
// 155.938 us; speedup vs baseline: 1.6688x; 1.6688x over previous
//
#include <hip/hip_runtime.h>
#include <hip/hip_bf16.h>
#include <stdint.h>

#define BATCH 2
#define S_LEN 2048
#define EMB   1024
#define NHEAD 16
#define HDIM  64

typedef __attribute__((ext_vector_type(8)))  __bf16 bf16x8;
typedef __attribute__((ext_vector_type(4)))  __bf16 bf16x4;
typedef __attribute__((ext_vector_type(4)))  float  f32x4;
typedef __attribute__((ext_vector_type(16))) float  f32x16;

#define ZERO16 ((f32x16){0.f,0.f,0.f,0.f,0.f,0.f,0.f,0.f,0.f,0.f,0.f,0.f,0.f,0.f,0.f,0.f})
#define SM_SCALE_LOG2 0.18033688011112042f  /* 0.125 * log2(e) */

static __device__ __forceinline__ void gload_lds16(const void* g, void* l) {
    __builtin_amdgcn_global_load_lds(
        (__attribute__((address_space(1))) void*)g,
        (__attribute__((address_space(3))) void*)l,
        16, 0, 0);
}

// ---------------------------------------------------------------------------
// fp32 -> bf16 conversions
// ---------------------------------------------------------------------------
__global__ void f2b_kernel(const float* __restrict__ s, __bf16* __restrict__ d, int n4) {
    int i = blockIdx.x * blockDim.x + threadIdx.x;
    if (i >= n4) return;
    float4 v = reinterpret_cast<const float4*>(s)[i];
    bf16x4 o = { (__bf16)v.x, (__bf16)v.y, (__bf16)v.z, (__bf16)v.w };
    reinterpret_cast<bf16x4*>(d)[i] = o;
}

__global__ void f2b4_kernel(const float* __restrict__ s0, const float* __restrict__ s1,
                            const float* __restrict__ s2, const float* __restrict__ s3,
                            __bf16* __restrict__ d0, __bf16* __restrict__ d1,
                            __bf16* __restrict__ d2, __bf16* __restrict__ d3, int n4) {
    int i = blockIdx.x * blockDim.x + threadIdx.x;
    if (i >= n4) return;
    const float* s = blockIdx.y == 0 ? s0 : blockIdx.y == 1 ? s1 : blockIdx.y == 2 ? s2 : s3;
    __bf16*      d = blockIdx.y == 0 ? d0 : blockIdx.y == 1 ? d1 : blockIdx.y == 2 ? d2 : d3;
    float4 v = reinterpret_cast<const float4*>(s)[i];
    bf16x4 o = { (__bf16)v.x, (__bf16)v.y, (__bf16)v.z, (__bf16)v.w };
    reinterpret_cast<bf16x4*>(d)[i] = o;
}

// ---------------------------------------------------------------------------
// 128x64-tile NT GEMM, fp32 output (final projection). Grid (N/64, M/128).
// ---------------------------------------------------------------------------
__global__ __launch_bounds__(256)
void gemm_o64(const __bf16* __restrict__ A, const __bf16* __restrict__ W,
              const float* __restrict__ bias, float* __restrict__ out,
              int M, int N, int K) {
    __shared__ __align__(16) __bf16 As[128 * 32];
    __shared__ __align__(16) __bf16 Bs[64 * 32];

    const int t    = threadIdx.x;
    const int w    = t >> 6;
    const int lane = t & 63;
    const int m0   = blockIdx.y * 128;
    const int n0   = blockIdx.x * 64;
    const int wr   = w * 32;
    const int fr   = lane & 15;
    const int kg   = (lane >> 4) * 8;

    f32x4 acc[2][4];
#pragma unroll
    for (int i = 0; i < 2; ++i)
#pragma unroll
        for (int n = 0; n < 4; ++n) acc[i][n] = (f32x4){0.f, 0.f, 0.f, 0.f};

    for (int kt = 0; kt < K; kt += 32) {
#pragma unroll
        for (int i = 0; i < 2; ++i) {
            int chunk = i * 256 + t;
            int row   = chunk >> 2;
            int col   = (chunk & 3) * 8;
            gload_lds16(A + (size_t)(m0 + row) * K + kt + col,
                        (char*)As + i * 4096 + w * 1024);
        }
        {
            int row = t >> 2;
            int col = (t & 3) * 8;
            gload_lds16(W + (size_t)(n0 + row) * K + kt + col,
                        (char*)Bs + w * 1024);
        }
        __syncthreads();

        bf16x8 af[2], bfv[4];
#pragma unroll
        for (int m = 0; m < 2; ++m)
            af[m] = *(const bf16x8*)&As[(wr + m * 16 + fr) * 32 + kg];
#pragma unroll
        for (int n = 0; n < 4; ++n)
            bfv[n] = *(const bf16x8*)&Bs[(n * 16 + fr) * 32 + kg];
#pragma unroll
        for (int m = 0; m < 2; ++m)
#pragma unroll
            for (int n = 0; n < 4; ++n)
                acc[m][n] = __builtin_amdgcn_mfma_f32_16x16x32_bf16(
                    af[m], bfv[n], acc[m][n], 0, 0, 0);
        __syncthreads();
    }

    const int rbase = (lane >> 4) * 4;
#pragma unroll
    for (int m = 0; m < 2; ++m) {
#pragma unroll
        for (int n = 0; n < 4; ++n) {
            int col  = n0 + n * 16 + fr;
            float bv = bias[col];
#pragma unroll
            for (int jj = 0; jj < 4; ++jj) {
                int row = m0 + wr + m * 16 + rbase + jj;
                out[(size_t)row * N + col] = acc[m][n][jj] + bv;
            }
        }
    }
}

// ---------------------------------------------------------------------------
// Fused QKV projection, 128x64 tiles: grid x = 48 (which*16 + nblk), y = 32.
// ---------------------------------------------------------------------------
__global__ __launch_bounds__(256)
void gemm_qkv64(const __bf16* __restrict__ A,
                const __bf16* __restrict__ W0p, const __bf16* __restrict__ W1p,
                const __bf16* __restrict__ W2p,
                const float* __restrict__ b0p, const float* __restrict__ b1p,
                const float* __restrict__ b2p,
                __bf16* __restrict__ o0, __bf16* __restrict__ o1,
                __bf16* __restrict__ o2, int M, int N, int K) {
    __shared__ __align__(16) __bf16 As[128 * 32];
    __shared__ __align__(16) __bf16 Bs[64 * 32];

    const int which = blockIdx.x >> 4;
    const __bf16* W    = which == 0 ? W0p : which == 1 ? W1p : W2p;
    const float*  bias = which == 0 ? b0p : which == 1 ? b1p : b2p;
    __bf16*       out  = which == 0 ? o0  : which == 1 ? o1  : o2;

    const int t    = threadIdx.x;
    const int w    = t >> 6;
    const int lane = t & 63;
    const int m0   = blockIdx.y * 128;
    const int n0   = (blockIdx.x & 15) * 64;
    const int wr   = w * 32;
    const int fr   = lane & 15;
    const int kg   = (lane >> 4) * 8;

    f32x4 acc[2][4];
#pragma unroll
    for (int i = 0; i < 2; ++i)
#pragma unroll
        for (int n = 0; n < 4; ++n) acc[i][n] = (f32x4){0.f, 0.f, 0.f, 0.f};

    for (int kt = 0; kt < K; kt += 32) {
#pragma unroll
        for (int i = 0; i < 2; ++i) {
            int chunk = i * 256 + t;
            int row   = chunk >> 2;
            int col   = (chunk & 3) * 8;
            gload_lds16(A + (size_t)(m0 + row) * K + kt + col,
                        (char*)As + i * 4096 + w * 1024);
        }
        {
            int row = t >> 2;
            int col = (t & 3) * 8;
            gload_lds16(W + (size_t)(n0 + row) * K + kt + col,
                        (char*)Bs + w * 1024);
        }
        __syncthreads();

        bf16x8 af[2], bfv[4];
#pragma unroll
        for (int m = 0; m < 2; ++m)
            af[m] = *(const bf16x8*)&As[(wr + m * 16 + fr) * 32 + kg];
#pragma unroll
        for (int n = 0; n < 4; ++n)
            bfv[n] = *(const bf16x8*)&Bs[(n * 16 + fr) * 32 + kg];
#pragma unroll
        for (int m = 0; m < 2; ++m)
#pragma unroll
            for (int n = 0; n < 4; ++n)
                acc[m][n] = __builtin_amdgcn_mfma_f32_16x16x32_bf16(
                    af[m], bfv[n], acc[m][n], 0, 0, 0);
        __syncthreads();
    }

    const int rbase = (lane >> 4) * 4;
#pragma unroll
    for (int m = 0; m < 2; ++m) {
#pragma unroll
        for (int n = 0; n < 4; ++n) {
            int col  = n0 + n * 16 + fr;
            float bv = bias[col];
#pragma unroll
            for (int jj = 0; jj < 4; ++jj) {
                int row = m0 + wr + m * 16 + rbase + jj;
                float v = acc[m][n][jj] + bv;
                int b = row >> 11, s = row & (S_LEN - 1);
                int hh = col >> 6, d = col & (HDIM - 1);
                out[(((size_t)(b * NHEAD + hh)) * S_LEN + s) * HDIM + d] = (__bf16)v;
            }
        }
    }
}

// ---------------------------------------------------------------------------
// Block-causal flash attention, split-KV 8-wave structure.
// launch_bounds (512,4): min-waves 6 forced VGPR<=~85 -> accumulator spill
// (VGPR=40, 330 MB scratch traffic, 2.4x slower). With (512,4) VGPR=64 and
// runtime occupancy is still 3 blocks/CU (LDS 50 KB < 53.3 KB limit).
// ---------------------------------------------------------------------------
__global__ __launch_bounds__(512, 4)
void attn4_kernel(const __bf16* __restrict__ Q, const __bf16* __restrict__ Kv,
                  const __bf16* __restrict__ V, __bf16* __restrict__ out) {
    __shared__ __align__(16) __bf16 Kt[2][128 * 64];   // 32 KB
    __shared__ __align__(16) __bf16 Vt[64 * 128];      // 16 KB
    __shared__ float bc[8][32];                        // 1 KB

    const int t    = threadIdx.x;
    const int w8   = t >> 6;
    const int lane = t & 63;
    const int h    = lane >> 5;
    const int q32  = lane & 31;
    const int j    = w8 & 3;
    const int h2   = w8 >> 2;
    const int bh   = blockIdx.x;   // 0..31
    const int yy   = blockIdx.y;   // 0..15
    const int qt   = (yy < 8) ? (15 - yy) : (yy - 8);   // heavy-first dispatch
    const int qb   = 4 * qt + j;

    const __bf16* Qp = Q  + (size_t)bh * S_LEN * HDIM;
    const __bf16* Kp = Kv + (size_t)bh * S_LEN * HDIM;
    const __bf16* Vp = V  + (size_t)bh * S_LEN * HDIM;

    const int qrow = qb * 32 + q32;

    bf16x8 qreg[4];
#pragma unroll
    for (int ks = 0; ks < 4; ++ks)
        qreg[ks] = *(const bf16x8*)&Qp[(size_t)qrow * HDIM + 16 * ks + 8 * h];

    f32x16 oacc0 = ZERO16, oacc1 = ZERO16;
    float mrun = -1e30f, lrun = 0.f;

    // ---- prologue: stage chunk 0 ----
    {
#pragma unroll
        for (int i = 0; i < 2; ++i) {
            int c16 = i * 512 + t;
            int key = c16 >> 3;
            int d0  = ((c16 & 7) ^ (key & 7)) * 8;
            gload_lds16(Kp + (size_t)key * HDIM + d0, (char*)&Kt[0][0] + c16 * 16);
        }
        bf16x8 vr[2];
#pragma unroll
        for (int i = 0; i < 2; ++i)
            vr[i] = *(const bf16x8*)&Vp[(size_t)(64 * h2 + lane) * HDIM + (4 * i + j) * 8];
        const int key = 64 * h2 + lane;
#pragma unroll
        for (int i = 0; i < 2; ++i) {
            int d0 = (4 * i + j) * 8;
#pragma unroll
            for (int e = 0; e < 8; ++e) {
                int d = d0 + e;
                int x = (d ^ (d >> 3)) & 15;
                Vt[d * 128 + (key ^ (x << 3))] = vr[i][e];
            }
        }
        __syncthreads();
    }

    for (int c = 0; c <= qt; ++c) {
        const int  cur = c & 1;
        const bool pre = (c < qt);
        bf16x8 vr[2];
        if (pre) {
            const int kb = (c + 1) * 128;
#pragma unroll
            for (int i = 0; i < 2; ++i) {
                int c16 = i * 512 + t;
                int key = c16 >> 3;
                int d0  = ((c16 & 7) ^ (key & 7)) * 8;
                gload_lds16(Kp + (size_t)(kb + key) * HDIM + d0,
                            (char*)&Kt[cur ^ 1][0] + c16 * 16);
            }
#pragma unroll
            for (int i = 0; i < 2; ++i)
                vr[i] = *(const bf16x8*)&Vp[(size_t)(kb + 64 * h2 + lane) * HDIM +
                                            (4 * i + j) * 8];
        }

        // causal sub-block count for this wave in this chunk
        int ns;
        if (pre) ns = 2;
        else     ns = h2 ? (j == 3 ? 2 : (j == 2 ? 1 : 0)) : (j == 0 ? 1 : 2);

        for (int u = 0; u < ns; ++u) {
            const int klocal = 64 * h2 + 32 * u;

            // S^T = K . Q^T
            f32x16 sac = ZERO16;
            __builtin_amdgcn_s_setprio(1);
#pragma unroll
            for (int ks = 0; ks < 4; ++ks) {
                bf16x8 kf = *(const bf16x8*)&Kt[cur][(klocal + q32) * 64 +
                                ((16 * ks + 8 * h) ^ ((q32 & 7) << 3))];
                sac = __builtin_amdgcn_mfma_f32_32x32x16_bf16(kf, qreg[ks], sac, 0, 0, 0);
            }
            __builtin_amdgcn_s_setprio(0);

            // softmax: max tree on raw scores, scale folded into FMA
            float rmax = sac[0];
#pragma unroll
            for (int r = 1; r < 16; ++r) rmax = fmaxf(rmax, sac[r]);
            float pmax = rmax * SM_SCALE_LOG2;
            pmax = fmaxf(pmax, __shfl_xor(pmax, 32));

            if (__any(pmax > mrun + 8.f)) {
                float mnew = fmaxf(mrun, pmax);
                float fac  = exp2f(mrun - mnew);
                mrun = mnew;
                lrun *= fac;
                bc[w8][q32] = fac;
                asm volatile("s_waitcnt lgkmcnt(0)" ::: "memory");
                __builtin_amdgcn_sched_barrier(0);
#pragma unroll
                for (int q2 = 0; q2 < 4; ++q2) {
                    f32x4 fv = *(const f32x4*)&bc[w8][8 * q2 + 4 * h];
#pragma unroll
                    for (int jj = 0; jj < 4; ++jj) {
                        oacc0[4 * q2 + jj] *= fv[jj];
                        oacc1[4 * q2 + jj] *= fv[jj];
                    }
                }
            }

            float ps = 0.f;
#pragma unroll
            for (int r = 0; r < 16; ++r) {
                float pv = exp2f(__builtin_fmaf(sac[r], SM_SCALE_LOG2, -mrun));
                ps += pv;
                sac[r] = pv;
            }
            ps += __shfl_xor(ps, 32);
            lrun += ps;

            // pack P rows pairwise to bf16 (hardware cvt_pk)
            unsigned L[4], H[4];
#pragma unroll
            for (int g = 0; g < 4; ++g) {
                asm("v_cvt_pk_bf16_f32 %0, %1, %2"
                    : "=v"(L[g]) : "v"(sac[4 * g]), "v"(sac[4 * g + 1]));
                asm("v_cvt_pk_bf16_f32 %0, %1, %2"
                    : "=v"(H[g]) : "v"(sac[4 * g + 2]), "v"(sac[4 * g + 3]));
            }

            __builtin_amdgcn_s_setprio(1);
#pragma unroll
            for (int s2 = 0; s2 < 2; ++s2) {
                unsigned a0 = L[2 * s2], b0 = L[2 * s2 + 1];
                unsigned a1 = H[2 * s2], b1 = H[2 * s2 + 1];
                asm("v_permlane32_swap_b32 %0, %1" : "+v"(a0), "+v"(b0));
                asm("v_permlane32_swap_b32 %0, %1" : "+v"(a1), "+v"(b1));
                unsigned wvw[4] = { a0, a1, b0, b1 };
                bf16x8 pa = *(bf16x8*)wvw;

                const int klb = klocal + 16 * s2;
#pragma unroll
                for (int n = 0; n < 2; ++n) {
                    int d = 32 * n + q32;
                    int x = (d ^ (d >> 3)) & 15;
                    bf16x8 vf = *(const bf16x8*)&Vt[d * 128 +
                                    ((klb + 8 * h) ^ (x << 3))];
                    if (n == 0)
                        oacc0 = __builtin_amdgcn_mfma_f32_32x32x16_bf16(pa, vf, oacc0, 0, 0, 0);
                    else
                        oacc1 = __builtin_amdgcn_mfma_f32_32x32x16_bf16(pa, vf, oacc1, 0, 0, 0);
                }
            }
            __builtin_amdgcn_s_setprio(0);
        }

        __syncthreads();                 // all reads of Vt & Kt[cur] done
        if (pre) {
            const int key = 64 * h2 + lane;
#pragma unroll
            for (int i = 0; i < 2; ++i) {
                int d0 = (4 * i + j) * 8;
#pragma unroll
                for (int e = 0; e < 8; ++e) {
                    int d = d0 + e;
                    int x = (d ^ (d >> 3)) & 15;
                    Vt[d * 128 + (key ^ (x << 3))] = vr[i][e];
                }
            }
            __syncthreads();             // Vt for chunk c+1 visible
        }
    }

    // ---- pair merge: waves (j, h2=0) <- (j, h2=1) ----
    float* MLm = (float*)&Vt[0];         // [8][32]
    float* MLl = MLm + 256;              // [8][32]
    float* Oex = (float*)&Kt[0][0];      // [4][32][64] f32 = 32 KB

    if (h == 0) { MLm[w8 * 32 + q32] = mrun; MLl[w8 * 32 + q32] = lrun; }
    if (h2 == 1) {
        float* ob = Oex + j * 2048;
#pragma unroll
        for (int q2 = 0; q2 < 4; ++q2)
#pragma unroll
            for (int jj = 0; jj < 4; ++jj) {
                int r  = 4 * q2 + jj;
                int rl = 8 * q2 + 4 * h + jj;
                ob[rl * 64 + q32]      = oacc0[r];
                ob[rl * 64 + 32 + q32] = oacc1[r];
            }
    }
    __syncthreads();

    if (h2 == 0) {
        const int b = bh >> 4, hh = bh & (NHEAD - 1);
        __bf16* op = out + (size_t)b * S_LEN * EMB + hh * HDIM;
        const float* ob = Oex + j * 2048;
#pragma unroll
        for (int q2 = 0; q2 < 4; ++q2) {
            f32x4 ma4 = *(const f32x4*)&MLm[j * 32 + 8 * q2 + 4 * h];
            f32x4 mb4 = *(const f32x4*)&MLm[(j + 4) * 32 + 8 * q2 + 4 * h];
            f32x4 la4 = *(const f32x4*)&MLl[j * 32 + 8 * q2 + 4 * h];
            f32x4 lb4 = *(const f32x4*)&MLl[(j + 4) * 32 + 8 * q2 + 4 * h];
#pragma unroll
            for (int jj = 0; jj < 4; ++jj) {
                float ma = ma4[jj], mb = mb4[jj];
                float mst = fmaxf(ma, mb);
                float sa  = exp2f(ma - mst), sb = exp2f(mb - mst);
                float inv = 1.f / (la4[jj] * sa + lb4[jj] * sb);
                int r  = 4 * q2 + jj;
                int rl = 8 * q2 + 4 * h + jj;
                int row = qb * 32 + rl;
                float v0 = (oacc0[r] * sa + ob[rl * 64 + q32] * sb) * inv;
                float v1 = (oacc1[r] * sa + ob[rl * 64 + 32 + q32] * sb) * inv;
                op[(size_t)row * EMB + q32]      = (__bf16)v0;
                op[(size_t)row * EMB + 32 + q32] = (__bf16)v1;
            }
        }
    }
}

// ---------------------------------------------------------------------------
extern "C" void kernel_launch(void* const* d_in, const int* in_sizes, int n_in,
                              void* d_out, int out_size, void* d_ws, size_t ws_size,
                              hipStream_t stream) {
    const float* x  = (const float*)d_in[0];
    const float* Wq = (const float*)d_in[1];
    const float* bq = (const float*)d_in[2];
    const float* Wk = (const float*)d_in[3];
    const float* bk = (const float*)d_in[4];
    const float* Wv = (const float*)d_in[5];
    const float* bv = (const float*)d_in[6];
    const float* Wo = (const float*)d_in[7];
    const float* bo = (const float*)d_in[8];
    float* out = (float*)d_out;

    char* ws = (char*)d_ws;
    __bf16* xb  = (__bf16*)(ws + 0);
    __bf16* wqb = (__bf16*)(ws + 8388608);
    __bf16* wkb = (__bf16*)(ws + 10485760);
    __bf16* wvb = (__bf16*)(ws + 12582912);
    __bf16* wob = (__bf16*)(ws + 14680064);
    __bf16* Qb  = (__bf16*)(ws + 16777216);
    __bf16* Kb  = (__bf16*)(ws + 25165824);
    __bf16* Vb  = (__bf16*)(ws + 33554432);
    __bf16* Ab  = (__bf16*)(ws + 41943040);

    const int M = BATCH * S_LEN;  // 4096
    const int N = EMB;            // 1024
    const int K = EMB;            // 1024

    f2b_kernel<<<(M * K / 4 + 255) / 256, 256, 0, stream>>>(x, xb, M * K / 4);
    f2b4_kernel<<<dim3(N * K / 4 / 256, 4), 256, 0, stream>>>(
        Wq, Wk, Wv, Wo, wqb, wkb, wvb, wob, N * K / 4);

    gemm_qkv64<<<dim3(48, M / 128), 256, 0, stream>>>(
        xb, wqb, wkb, wvb, bq, bk, bv, Qb, Kb, Vb, M, N, K);

    attn4_kernel<<<dim3(BATCH * NHEAD, S_LEN / 128), 512, 0, stream>>>(Qb, Kb, Vb, Ab);

    gemm_o64<<<dim3(16, M / 128), 256, 0, stream>>>(Ab, wob, bo, out, M, N, K);
}